// Round 2
// baseline (103.688 us; speedup 1.0000x reference)
//
#include <hip/hip_runtime.h>
#include <stdint.h>

#define HSZ 2048
#define PRIME 500009u

typedef __attribute__((ext_vector_type(8))) short short8;
typedef __attribute__((ext_vector_type(4))) float f32x4;

// fp32 -> bf16 round-to-nearest-even (no NaN inputs here)
__device__ __forceinline__ short f2bf(float f) {
  union { float f; unsigned u; } v; v.f = f;
  unsigned u = v.u;
  unsigned r = (u + 0x7FFFu + ((u >> 16) & 1u)) >> 16;
  return (short)(unsigned short)r;
}

// load 8 consecutive fp32, convert to bf16x8 fragment
__device__ __forceinline__ short8 load8_bf(const float* __restrict__ p) {
  float4 a = *reinterpret_cast<const float4*>(p);
  float4 b = *reinterpret_cast<const float4*>(p + 4);
  short8 r;
  r[0] = f2bf(a.x); r[1] = f2bf(a.y); r[2] = f2bf(a.z); r[3] = f2bf(a.w);
  r[4] = f2bf(b.x); r[5] = f2bf(b.y); r[6] = f2bf(b.z); r[7] = f2bf(b.w);
  return r;
}

// -------- Kernel 1: hash + gather + (embvec @ Wh.T) -> emb0[16384][32] f32 --------
// 1024 blocks x 256 threads; 16 tokens/block; all 4 waves busy (2 e-tiles x 2 K-halves).
__global__ __launch_bounds__(256, 4) void emb0_kernel(
    const int* __restrict__ ids, const int* __restrict__ mapping,
    const unsigned* __restrict__ mult, const float* __restrict__ table,
    const float* __restrict__ Wh, float* __restrict__ emb0) {
  __shared__ __align__(16) short A_lds[16][264];  // [token][256 bf16 + pad]
  __shared__ int idx_lds[128];                    // 16 tokens x 8 heads
  __shared__ float pred[2][64][4];                // K-half partials per e-tile
  const int tid = threadIdx.x;
  const int t0 = blockIdx.x * 16;

  // 1) hash indices: thread = (token, head)
  if (tid < 128) {
    int t_loc = tid >> 3, head = tid & 7;
    int tg = t0 + t_loc;
    int b = tg >> 12, s = tg & 4095;
    const int* idb = ids + (b << 12);
    int s1 = s + 1 > 4095 ? 4095 : s + 1;
    int s2 = s + 2 > 4095 ? 4095 : s + 2;
    uint64_t c0 = (unsigned)mapping[idb[s]];
    uint64_t c1 = (unsigned)mapping[idb[s1]];
    uint64_t c2 = (unsigned)mapping[idb[s2]];
    int mb = head * 3;  // head = oi*4 + hd; multipliers row-major [2][4][3]
    uint64_t h = (c0 * (uint64_t)mult[mb]) ^ (c1 * (uint64_t)mult[mb + 1]);
    if (head >= 4) h ^= c2 * (uint64_t)mult[mb + 2];  // trigram order
    unsigned row = (unsigned)(h % PRIME) + (unsigned)head * PRIME;
    idx_lds[tid] = (int)row;
  }
  __syncthreads();

  // 2) gather 128 table rows -> LDS bf16 (8 lanes per 128B row, coalesced; 4 indep loads/thread)
  #pragma unroll
  for (int p = 0; p < 4; ++p) {
    int task = p * 256 + tid;
    int r = task >> 3;
    int c4 = (task & 7) * 4;
    long row = idx_lds[r];
    float4 v = *reinterpret_cast<const float4*>(table + row * 32 + c4);
    int tl = r >> 3, hd = r & 7;
    short* dst = &A_lds[tl][hd * 32 + c4];
    dst[0] = f2bf(v.x); dst[1] = f2bf(v.y); dst[2] = f2bf(v.z); dst[3] = f2bf(v.w);
  }
  __syncthreads();

  // 3) MFMA: wave = (e-tile, K-half); K=128 per wave over 4 ksteps
  int wid = tid >> 6, lane = tid & 63;
  int e0 = (wid & 1) * 16, kh = wid >> 1;
  int l16 = lane & 15, q = lane >> 4;
  f32x4 acc = {0.f, 0.f, 0.f, 0.f};
  #pragma unroll
  for (int ks = 0; ks < 4; ++ks) {
    short8 b = load8_bf(Wh + (size_t)(e0 + l16) * 256 + kh * 128 + ks * 32 + q * 8);
    short8 a = *reinterpret_cast<const short8*>(&A_lds[l16][kh * 128 + ks * 32 + q * 8]);
    acc = __builtin_amdgcn_mfma_f32_16x16x32_bf16(a, b, acc, 0, 0, 0);
  }
  if (kh == 1) {
    #pragma unroll
    for (int j = 0; j < 4; ++j) pred[wid & 1][lane][j] = acc[j];
  }
  __syncthreads();
  if (kh == 0) {
    // C layout (verified): col = lane&15, row = (lane>>4)*4 + j
    #pragma unroll
    for (int j = 0; j < 4; ++j) {
      float v = acc[j] + pred[wid & 1][lane][j];
      int t = t0 + q * 4 + j;
      emb0[(size_t)t * 32 + e0 + l16] = v;
    }
  }
}

// -------- Kernel 2: conv + gate(sigmoid(hidden@Wg.T)) * emb, then @ Wo.T --------
// 1024 blocks x 256 threads; 16 tokens/block; all 4 waves busy in every phase.
__global__ __launch_bounds__(256, 4) void fuse_kernel(
    const float* __restrict__ hidden, const float* __restrict__ emb0,
    const float* __restrict__ cw, const float* __restrict__ cb,
    const float* __restrict__ Wg, const float* __restrict__ Wo,
    float* __restrict__ out) {
  __shared__ float emb_lds[16][33];
  __shared__ __align__(16) short ge_lds[16][40];
  __shared__ float accred[4][8][64];  // [kq][reg][lane] — conflict-free stores/reads
  const int tid = threadIdx.x;
  const int t0 = blockIdx.x * 16;

  // conv preamble: emb[t,e] = cb[e] + sum_j cw[e,j] * emb0[t-3+j, e] (zero-pad per batch)
  #pragma unroll
  for (int it = 0; it < 2; ++it) {
    int ii = it * 256 + tid;
    int tl = ii >> 5, e = ii & 31;
    int s = (t0 + tl) & 4095;
    float a = cb[e];
    #pragma unroll
    for (int j = 0; j < 4; ++j) {
      int sp = s - 3 + j;
      if (sp >= 0) a += cw[e * 4 + j] * emb0[(size_t)(t0 + tl - 3 + j) * 32 + e];
    }
    emb_lds[tl][e] = a;
  }

  int wid = tid >> 6, lane = tid & 63;
  int l16 = lane & 15, q = lane >> 4;

  // ---- phase A: gate matmul, K=2048 split 4 ways across waves (512 each) ----
  f32x4 acc0 = {0, 0, 0, 0}, acc1 = {0, 0, 0, 0};
  const float* hrow = hidden + (size_t)(t0 + l16) * HSZ + wid * 512 + q * 8;
  const float* wg0 = Wg + (size_t)l16 * HSZ + wid * 512 + q * 8;
  const float* wg1 = Wg + (size_t)(16 + l16) * HSZ + wid * 512 + q * 8;
  for (int kc = 0; kc < 4; ++kc) {
    short8 B0[4], B1[4], A[4];
    #pragma unroll
    for (int ks = 0; ks < 4; ++ks) {
      B0[ks] = load8_bf(wg0 + kc * 128 + ks * 32);
      B1[ks] = load8_bf(wg1 + kc * 128 + ks * 32);
      A[ks] = load8_bf(hrow + kc * 128 + ks * 32);
    }
    #pragma unroll
    for (int ks = 0; ks < 4; ++ks) {
      acc0 = __builtin_amdgcn_mfma_f32_16x16x32_bf16(A[ks], B0[ks], acc0, 0, 0, 0);
      acc1 = __builtin_amdgcn_mfma_f32_16x16x32_bf16(A[ks], B1[ks], acc1, 0, 0, 0);
    }
  }
  #pragma unroll
  for (int j = 0; j < 4; ++j) {
    accred[wid][j][lane] = acc0[j];
    accred[wid][4 + j][lane] = acc1[j];
  }
  __syncthreads();

  // reduce 4 K-partials + sigmoid + multiply conv output; 2 outputs/thread
  #pragma unroll
  for (int p = 0; p < 2; ++p) {
    int o = p * 256 + tid;
    int r = o >> 5, c = o & 31;
    int ln = (c & 15) + ((r >> 2) << 4);
    int rg = (r & 3) + ((c >> 4) << 2);
    float s = accred[0][rg][ln] + accred[1][rg][ln] + accred[2][rg][ln] + accred[3][rg][ln];
    float g = 1.f / (1.f + __expf(-s));
    ge_lds[r][c] = f2bf(g * emb_lds[r][c]);
  }
  __syncthreads();

  // ---- phase B: out[t,h] = ge @ Wo.T; wave handles 512 h-cols (32 tiles) ----
  short8 Af = *reinterpret_cast<const short8*>(&ge_lds[l16][q * 8]);
  for (int ht = 0; ht < 32; ++ht) {
    int h0 = wid * 512 + ht * 16;
    short8 bo = load8_bf(Wo + (size_t)(h0 + l16) * 32 + q * 8);
    f32x4 z = {0, 0, 0, 0};
    f32x4 o0 = __builtin_amdgcn_mfma_f32_16x16x32_bf16(Af, bo, z, 0, 0, 0);
    #pragma unroll
    for (int j = 0; j < 4; ++j)
      out[(size_t)(t0 + q * 4 + j) * HSZ + h0 + l16] = o0[j];
  }
}

extern "C" void kernel_launch(void* const* d_in, const int* in_sizes, int n_in,
                              void* d_out, int out_size, void* d_ws, size_t ws_size,
                              hipStream_t stream) {
  const int* ids = (const int*)d_in[0];
  const float* hidden = (const float*)d_in[1];
  const int* mapping = (const int*)d_in[2];
  const unsigned* mult = (const unsigned*)d_in[3];  // int64 delivered as int32; low bits exact
  const float* table = (const float*)d_in[4];
  const float* cw = (const float*)d_in[5];
  const float* cb = (const float*)d_in[6];
  const float* Wh = (const float*)d_in[7];
  const float* Wg = (const float*)d_in[8];
  const float* Wo = (const float*)d_in[9];
  float* out = (float*)d_out;
  float* emb0 = (float*)d_ws;  // 16384 x 32 f32 = 2 MiB scratch

  emb0_kernel<<<1024, 256, 0, stream>>>(ids, mapping, mult, table, Wh, emb0);
  fuse_kernel<<<1024, 256, 0, stream>>>(hidden, emb0, cw, cb, Wg, Wo, out);
}

// Round 3
// 92.698 us; speedup vs baseline: 1.1186x; 1.1186x over previous
//
#include <hip/hip_runtime.h>
#include <hip/hip_bf16.h>
#include <stdint.h>

#define HSZ 2048
#define PRIME 500009u

typedef __attribute__((ext_vector_type(8))) short short8;
typedef __attribute__((ext_vector_type(4))) float f32x4;
typedef __attribute__((ext_vector_type(4))) unsigned uint4v;
typedef __attribute__((ext_vector_type(2))) unsigned uint2v;

// hw bf16 cvt (v_cvt_pk_bf16_f32), RNE
__device__ __forceinline__ unsigned pk2(float x, float y) {
  __hip_bfloat162 h = __float22bfloat162_rn(make_float2(x, y));
  return *reinterpret_cast<unsigned*>(&h);
}
__device__ __forceinline__ short f2bf(float f) {
  __hip_bfloat16 h = __float2bfloat16(f);
  return *reinterpret_cast<short*>(&h);
}

// load 8 consecutive fp32 -> bf16x8 fragment (4x cvt_pk)
__device__ __forceinline__ short8 load8_bf(const float* __restrict__ p) {
  float4 a = *reinterpret_cast<const float4*>(p);
  float4 b = *reinterpret_cast<const float4*>(p + 4);
  uint4v u = {pk2(a.x, a.y), pk2(a.z, a.w), pk2(b.x, b.y), pk2(b.z, b.w)};
  return __builtin_bit_cast(short8, u);
}

// -------- Kernel 1: hash + gather + (embvec @ Wh.T) -> emb0[16384][32] f32 --------
// 512 blocks x 256 threads; 32 tokens/block.
__global__ __launch_bounds__(256) void emb0_kernel(
    const int* __restrict__ ids, const int* __restrict__ mapping,
    const unsigned* __restrict__ mult, const float* __restrict__ table,
    const float* __restrict__ Wh, float* __restrict__ emb0) {
  __shared__ __align__(16) short A_lds[32][264];  // [token][256 bf16 + pad8]
  __shared__ int idx_lds[256];                    // 32 tokens x 8 heads
  const int tid = threadIdx.x;
  const int t0 = blockIdx.x * 32;

  // 1) hash indices: thread = (token, head)
  {
    int t_loc = tid >> 3, head = tid & 7;
    int tg = t0 + t_loc;
    int b = tg >> 12, s = tg & 4095;
    const int* idb = ids + (b << 12);
    int s1 = s + 1 > 4095 ? 4095 : s + 1;
    int s2 = s + 2 > 4095 ? 4095 : s + 2;
    uint64_t c0 = (unsigned)mapping[idb[s]];
    uint64_t c1 = (unsigned)mapping[idb[s1]];
    uint64_t c2 = (unsigned)mapping[idb[s2]];
    int mb = head * 3;  // head = oi*4 + hd; multipliers row-major [2][4][3]
    uint64_t h = (c0 * (uint64_t)mult[mb]) ^ (c1 * (uint64_t)mult[mb + 1]);
    if (head >= 4) h ^= c2 * (uint64_t)mult[mb + 2];  // trigram order
    unsigned row = (unsigned)(h % PRIME) + (unsigned)head * PRIME;
    idx_lds[tid] = (int)row;
  }
  __syncthreads();

  // 2) gather table rows -> LDS bf16 (8 lanes per 128B row; 8B packed LDS writes)
  #pragma unroll
  for (int p = 0; p < 8; ++p) {
    int r = p * 32 + (tid >> 3);
    int c4 = (tid & 7) * 4;
    long row = idx_lds[r];
    float4 v = *reinterpret_cast<const float4*>(table + row * 32 + c4);
    int tl = r >> 3, hd = r & 7;
    uint2v pk = {pk2(v.x, v.y), pk2(v.z, v.w)};
    *reinterpret_cast<uint2v*>(&A_lds[tl][hd * 32 + c4]) = pk;
  }
  __syncthreads();

  // 3) MFMA: wave = (token-tile, e-coltile); K=256 over 8 ksteps.
  // Operands SWAPPED (A=Wh rows, B=token vecs) so D row-dim = e -> float4 store.
  int wid = tid >> 6, lane = tid & 63;
  int tt = wid >> 1, e0 = (wid & 1) * 16;
  int l16 = lane & 15, q = lane >> 4;
  short8 Wf[8];
  #pragma unroll
  for (int ks = 0; ks < 8; ++ks)
    Wf[ks] = load8_bf(Wh + (size_t)(e0 + l16) * 256 + ks * 32 + q * 8);
  f32x4 acc = {0.f, 0.f, 0.f, 0.f};
  #pragma unroll
  for (int ks = 0; ks < 8; ++ks) {
    short8 a = *reinterpret_cast<const short8*>(&A_lds[tt * 16 + l16][ks * 32 + q * 8]);
    acc = __builtin_amdgcn_mfma_f32_16x16x32_bf16(Wf[ks], a, acc, 0, 0, 0);
  }
  // D: col(lane&15)=token, row((lane>>4)*4+j)=e  -> lane writes 4 consecutive e
  int t = t0 + tt * 16 + l16;
  *reinterpret_cast<f32x4*>(&emb0[(size_t)t * 32 + e0 + q * 4]) = acc;
}

// -------- Kernel 2: conv + gate(sigmoid(hidden@Wg.T)) * emb, then @ Wo.T --------
// 512 blocks x 256 threads; 32 tokens/block.
__global__ __launch_bounds__(256) void fuse_kernel(
    const float* __restrict__ hidden, const float* __restrict__ emb0,
    const float* __restrict__ cw, const float* __restrict__ cb,
    const float* __restrict__ Wg, const float* __restrict__ Wo,
    float* __restrict__ out) {
  __shared__ float emb_lds[32][33];
  __shared__ __align__(16) short ge_lds[32][40];
  __shared__ float accred[2][64][8];
  const int tid = threadIdx.x;
  const int t0 = blockIdx.x * 32;

  // conv preamble: emb[t,e] = cb[e] + sum_j cw[e,j] * emb0[t-3+j, e] (zero-pad per batch)
  #pragma unroll
  for (int it = 0; it < 4; ++it) {
    int ii = it * 256 + tid;
    int tl = ii >> 5, e = ii & 31;
    int s = (t0 + tl) & 4095;
    float a = cb[e];
    #pragma unroll
    for (int j = 0; j < 4; ++j) {
      int sp = s - 3 + j;
      if (sp >= 0) a += cw[e * 4 + j] * emb0[(size_t)(t0 + tl - 3 + j) * 32 + e];
    }
    emb_lds[tl][e] = a;
  }

  int wid = tid >> 6, lane = tid & 63;
  int l16 = lane & 15, q = lane >> 4;
  int tt = wid & 1, kh = wid >> 1;

  // ---- phase A: gate matmul, K=2048; waves = (token-tile x K-half) ----
  f32x4 acc0 = {0, 0, 0, 0}, acc1 = {0, 0, 0, 0};
  const float* hrow = hidden + (size_t)(t0 + tt * 16 + l16) * HSZ + kh * 1024 + q * 8;
  const float* wg0 = Wg + (size_t)l16 * HSZ + kh * 1024 + q * 8;
  const float* wg1 = Wg + (size_t)(16 + l16) * HSZ + kh * 1024 + q * 8;
  for (int kc = 0; kc < 4; ++kc) {
    short8 B0[8], B1[8];
    #pragma unroll
    for (int ks = 0; ks < 8; ++ks) {
      B0[ks] = load8_bf(wg0 + kc * 256 + ks * 32);
      B1[ks] = load8_bf(wg1 + kc * 256 + ks * 32);
    }
    #pragma unroll
    for (int ks = 0; ks < 8; ++ks) {
      short8 a = load8_bf(hrow + kc * 256 + ks * 32);
      acc0 = __builtin_amdgcn_mfma_f32_16x16x32_bf16(a, B0[ks], acc0, 0, 0, 0);
      acc1 = __builtin_amdgcn_mfma_f32_16x16x32_bf16(a, B1[ks], acc1, 0, 0, 0);
    }
  }
  if (kh == 1) {
    #pragma unroll
    for (int j = 0; j < 4; ++j) {
      accred[tt][lane][j] = acc0[j];
      accred[tt][lane][4 + j] = acc1[j];
    }
  }
  __syncthreads();
  if (kh == 0) {
    #pragma unroll
    for (int j = 0; j < 4; ++j) {
      acc0[j] += accred[tt][lane][j];
      acc1[j] += accred[tt][lane][4 + j];
    }
    // D (phase A, unswapped): col=lane&15 -> gate-col e, row=q*4+j -> token
    #pragma unroll
    for (int j = 0; j < 4; ++j) {
      int r = tt * 16 + q * 4 + j;
      float g0 = 1.f / (1.f + __expf(-acc0[j]));
      ge_lds[r][l16] = f2bf(g0 * emb_lds[r][l16]);
      float g1 = 1.f / (1.f + __expf(-acc1[j]));
      ge_lds[r][16 + l16] = f2bf(g1 * emb_lds[r][16 + l16]);
    }
  }
  __syncthreads();

  // ---- phase B: out[t,h] = ge @ Wo.T, operands swapped -> float4 stores ----
  short8 Af0 = *reinterpret_cast<const short8*>(&ge_lds[l16][q * 8]);
  short8 Af1 = *reinterpret_cast<const short8*>(&ge_lds[16 + l16][q * 8]);
  float* orow0 = out + (size_t)(t0 + l16) * HSZ;
  float* orow1 = out + (size_t)(t0 + 16 + l16) * HSZ;
  int hbase = wid * 512;
  for (int ht = 0; ht < 32; ++ht) {
    int h0 = hbase + ht * 16;
    short8 aw = load8_bf(Wo + (size_t)(h0 + l16) * 32 + q * 8);
    f32x4 z = {0, 0, 0, 0};
    // D: col=token (lane&15), row=h-offset (q*4+j) -> 4 consecutive h per lane
    f32x4 o0 = __builtin_amdgcn_mfma_f32_16x16x32_bf16(aw, Af0, z, 0, 0, 0);
    f32x4 o1 = __builtin_amdgcn_mfma_f32_16x16x32_bf16(aw, Af1, z, 0, 0, 0);
    *reinterpret_cast<f32x4*>(orow0 + h0 + q * 4) = o0;
    *reinterpret_cast<f32x4*>(orow1 + h0 + q * 4) = o1;
  }
}

extern "C" void kernel_launch(void* const* d_in, const int* in_sizes, int n_in,
                              void* d_out, int out_size, void* d_ws, size_t ws_size,
                              hipStream_t stream) {
  const int* ids = (const int*)d_in[0];
  const float* hidden = (const float*)d_in[1];
  const int* mapping = (const int*)d_in[2];
  const unsigned* mult = (const unsigned*)d_in[3];  // int64 delivered as int32; low bits exact
  const float* table = (const float*)d_in[4];
  const float* cw = (const float*)d_in[5];
  const float* cb = (const float*)d_in[6];
  const float* Wh = (const float*)d_in[7];
  const float* Wg = (const float*)d_in[8];
  const float* Wo = (const float*)d_in[9];
  float* out = (float*)d_out;
  float* emb0 = (float*)d_ws;  // 16384 x 32 f32 = 2 MiB scratch

  emb0_kernel<<<512, 256, 0, stream>>>(ids, mapping, mult, table, Wh, emb0);
  fuse_kernel<<<512, 256, 0, stream>>>(hidden, emb0, cw, cb, Wg, Wo, out);
}

// Round 4
// 90.782 us; speedup vs baseline: 1.1422x; 1.0211x over previous
//
#include <hip/hip_runtime.h>
#include <hip/hip_bf16.h>
#include <stdint.h>

#define HSZ 2048
#define PRIME 500009u

typedef __attribute__((ext_vector_type(8))) short short8;
typedef __attribute__((ext_vector_type(4))) float f32x4;
typedef __attribute__((ext_vector_type(4))) unsigned uint4v;
typedef __attribute__((ext_vector_type(2))) unsigned uint2v;

// hw bf16 cvt (v_cvt_pk_bf16_f32), RNE
__device__ __forceinline__ unsigned pk2(float x, float y) {
  __hip_bfloat162 h = __float22bfloat162_rn(make_float2(x, y));
  return *reinterpret_cast<unsigned*>(&h);
}
__device__ __forceinline__ short f2bf(float f) {
  __hip_bfloat16 h = __float2bfloat16(f);
  return *reinterpret_cast<short*>(&h);
}
__device__ __forceinline__ short8 pack8(float4 a, float4 b) {
  uint4v u = {pk2(a.x, a.y), pk2(a.z, a.w), pk2(b.x, b.y), pk2(b.z, b.w)};
  return __builtin_bit_cast(short8, u);
}
// load 8 consecutive fp32 -> bf16x8 fragment
__device__ __forceinline__ short8 load8_bf(const float* __restrict__ p) {
  float4 a = *reinterpret_cast<const float4*>(p);
  float4 b = *reinterpret_cast<const float4*>(p + 4);
  return pack8(a, b);
}
// async global->LDS, 16B per lane, LDS dest = uniform base + lane*16 (linear)
__device__ __forceinline__ void gload_lds16(const float* g, void* l) {
  __builtin_amdgcn_global_load_lds(
      (const __attribute__((address_space(1))) void*)g,
      (__attribute__((address_space(3))) void*)l, 16, 0, 0);
}

// -------- Kernel 1: hash + gather + (embvec @ Wh.T) -> emb0[16384][32] f32 --------
// 512 blocks x 256 threads; 32 tokens/block. (unchanged from round 3)
__global__ __launch_bounds__(256) void emb0_kernel(
    const int* __restrict__ ids, const int* __restrict__ mapping,
    const unsigned* __restrict__ mult, const float* __restrict__ table,
    const float* __restrict__ Wh, float* __restrict__ emb0) {
  __shared__ __align__(16) short A_lds[32][264];
  __shared__ int idx_lds[256];
  const int tid = threadIdx.x;
  const int t0 = blockIdx.x * 32;

  {
    int t_loc = tid >> 3, head = tid & 7;
    int tg = t0 + t_loc;
    int b = tg >> 12, s = tg & 4095;
    const int* idb = ids + (b << 12);
    int s1 = s + 1 > 4095 ? 4095 : s + 1;
    int s2 = s + 2 > 4095 ? 4095 : s + 2;
    uint64_t c0 = (unsigned)mapping[idb[s]];
    uint64_t c1 = (unsigned)mapping[idb[s1]];
    uint64_t c2 = (unsigned)mapping[idb[s2]];
    int mb = head * 3;
    uint64_t h = (c0 * (uint64_t)mult[mb]) ^ (c1 * (uint64_t)mult[mb + 1]);
    if (head >= 4) h ^= c2 * (uint64_t)mult[mb + 2];
    unsigned row = (unsigned)(h % PRIME) + (unsigned)head * PRIME;
    idx_lds[tid] = (int)row;
  }
  __syncthreads();

  #pragma unroll
  for (int p = 0; p < 8; ++p) {
    int r = p * 32 + (tid >> 3);
    int c4 = (tid & 7) * 4;
    long row = idx_lds[r];
    float4 v = *reinterpret_cast<const float4*>(table + row * 32 + c4);
    int tl = r >> 3, hd = r & 7;
    uint2v pk = {pk2(v.x, v.y), pk2(v.z, v.w)};
    *reinterpret_cast<uint2v*>(&A_lds[tl][hd * 32 + c4]) = pk;
  }
  __syncthreads();

  int wid = tid >> 6, lane = tid & 63;
  int tt = wid >> 1, e0 = (wid & 1) * 16;
  int l16 = lane & 15, q = lane >> 4;
  short8 Wf[8];
  #pragma unroll
  for (int ks = 0; ks < 8; ++ks)
    Wf[ks] = load8_bf(Wh + (size_t)(e0 + l16) * 256 + ks * 32 + q * 8);
  f32x4 acc = {0.f, 0.f, 0.f, 0.f};
  #pragma unroll
  for (int ks = 0; ks < 8; ++ks) {
    short8 a = *reinterpret_cast<const short8*>(&A_lds[tt * 16 + l16][ks * 32 + q * 8]);
    acc = __builtin_amdgcn_mfma_f32_16x16x32_bf16(Wf[ks], a, acc, 0, 0, 0);
  }
  int t = t0 + tt * 16 + l16;
  *reinterpret_cast<f32x4*>(&emb0[(size_t)t * 32 + e0 + q * 4]) = acc;
}

// -------- Kernel 2: conv + gate(sigmoid(hidden@Wg.T)) * emb, then @ Wo.T --------
// 512 blocks x 256 threads; 32 tokens/block. Hidden staged via global_load_lds,
// double-buffered, XOR-swizzled (source-side + read-side, T21).
__global__ __launch_bounds__(256) void fuse_kernel(
    const float* __restrict__ hidden, const float* __restrict__ emb0,
    const float* __restrict__ cw, const float* __restrict__ cb,
    const float* __restrict__ Wg, const float* __restrict__ Wo,
    float* __restrict__ out) {
  __shared__ __align__(16) float hbuf[2][32][256];  // 64 KB double buffer
  __shared__ float emb_lds[32][33];
  __shared__ __align__(16) short ge_lds[32][40];
  const int tid = threadIdx.x;
  const int wid = tid >> 6, lane = tid & 63;
  const int l16 = lane & 15, q = lane >> 4;
  const int t0 = blockIdx.x * 32;

  // stage one 32x256-f32 chunk of hidden into hbuf[buf]; wave w stages rows w*8..w*8+7.
  // LDS dest linear (row*1024 + lane*16); global src pre-swizzled byte^((row&7)<<4).
  auto STAGE = [&](int buf, int kc) {
    #pragma unroll
    for (int j = 0; j < 8; ++j) {
      int r = wid * 8 + j;
      unsigned so = ((unsigned)(lane * 16) ^ (((unsigned)r & 7) << 4)) >> 2;
      const float* src = hidden + (size_t)(t0 + r) * HSZ + kc * 256 + so;
      gload_lds16(src, &hbuf[buf][r][0]);
    }
  };

  STAGE(0, 0);

  // conv preamble (overlaps stage-0 flight):
  // emb[t,e] = cb[e] + sum_j cw[e,j]*emb0[t-3+j,e], zero-pad at batch start
  #pragma unroll
  for (int it = 0; it < 4; ++it) {
    int ii = it * 256 + tid;
    int tl = ii >> 5, e = ii & 31;
    int s = (t0 + tl) & 4095;
    float a = cb[e];
    #pragma unroll
    for (int j = 0; j < 4; ++j) {
      int sp = s - 3 + j;
      if (sp >= 0) a += cw[e * 4 + j] * emb0[(size_t)(t0 + tl - 3 + j) * 32 + e];
    }
    emb_lds[tl][e] = a;
  }
  __syncthreads();  // drains vmcnt(0): buf0 + emb_lds ready

  // ---- phase A: wave (tt,ee) owns gate tile [tt*16,+16) x [ee*16,+16), full K ----
  const int tt = wid >> 1, ee = wid & 1;
  const int R = tt * 16 + l16;                 // token row this lane reads
  const unsigned sw = ((unsigned)R & 7) << 4;  // read-side XOR (matches source-side)
  const char* hrow0 = (const char*)&hbuf[0][0][0] + R * 1024;
  const char* hrow1 = (const char*)&hbuf[1][0][0] + R * 1024;
  const float* wgp = Wg + (size_t)(ee * 16 + l16) * HSZ + q * 8;
  f32x4 acc = {0.f, 0.f, 0.f, 0.f};
  for (int kc = 0; kc < 8; ++kc) {
    if (kc < 7) STAGE((kc + 1) & 1, kc + 1);   // prefetch flies under compute
    const char* hb = (kc & 1) ? hrow1 : hrow0;
    short8 A[8], B[8];
    #pragma unroll
    for (int ks = 0; ks < 8; ++ks) {
      B[ks] = load8_bf(wgp + kc * 256 + ks * 32);
      unsigned b0 = (unsigned)(ks * 128 + q * 32);
      float4 a0 = *reinterpret_cast<const float4*>(hb + (b0 ^ sw));
      float4 a1 = *reinterpret_cast<const float4*>(hb + ((b0 + 16) ^ sw));
      A[ks] = pack8(a0, a1);
    }
    #pragma unroll
    for (int ks = 0; ks < 8; ++ks)
      acc = __builtin_amdgcn_mfma_f32_16x16x32_bf16(A[ks], B[ks], acc, 0, 0, 0);
    __syncthreads();  // drains stage(kc+1); all waves done with buf[kc&1]
  }

  // gate + multiply conv emb -> ge_lds (each wave writes its own quadrant)
  #pragma unroll
  for (int j = 0; j < 4; ++j) {
    int r = tt * 16 + q * 4 + j, c = ee * 16 + l16;
    float g = 1.f / (1.f + __expf(-acc[j]));
    ge_lds[r][c] = f2bf(g * emb_lds[r][c]);
  }
  __syncthreads();

  // ---- phase B: out[t,h] = ge @ Wo.T, swapped operands -> float4 stores ----
  short8 Af0 = *reinterpret_cast<const short8*>(&ge_lds[l16][q * 8]);
  short8 Af1 = *reinterpret_cast<const short8*>(&ge_lds[16 + l16][q * 8]);
  float* orow0 = out + (size_t)(t0 + l16) * HSZ;
  float* orow1 = out + (size_t)(t0 + 16 + l16) * HSZ;
  int hbase = wid * 512;
  for (int ht = 0; ht < 32; ++ht) {
    int h0 = hbase + ht * 16;
    short8 aw = load8_bf(Wo + (size_t)(h0 + l16) * 32 + q * 8);
    f32x4 z = {0, 0, 0, 0};
    f32x4 o0 = __builtin_amdgcn_mfma_f32_16x16x32_bf16(aw, Af0, z, 0, 0, 0);
    f32x4 o1 = __builtin_amdgcn_mfma_f32_16x16x32_bf16(aw, Af1, z, 0, 0, 0);
    *reinterpret_cast<f32x4*>(orow0 + h0 + q * 4) = o0;
    *reinterpret_cast<f32x4*>(orow1 + h0 + q * 4) = o1;
  }
}

extern "C" void kernel_launch(void* const* d_in, const int* in_sizes, int n_in,
                              void* d_out, int out_size, void* d_ws, size_t ws_size,
                              hipStream_t stream) {
  const int* ids = (const int*)d_in[0];
  const float* hidden = (const float*)d_in[1];
  const int* mapping = (const int*)d_in[2];
  const unsigned* mult = (const unsigned*)d_in[3];  // int64 delivered as int32; low bits exact
  const float* table = (const float*)d_in[4];
  const float* cw = (const float*)d_in[5];
  const float* cb = (const float*)d_in[6];
  const float* Wh = (const float*)d_in[7];
  const float* Wg = (const float*)d_in[8];
  const float* Wo = (const float*)d_in[9];
  float* out = (float*)d_out;
  float* emb0 = (float*)d_ws;  // 16384 x 32 f32 = 2 MiB scratch

  emb0_kernel<<<512, 256, 0, stream>>>(ids, mapping, mult, table, Wh, emb0);
  fuse_kernel<<<512, 256, 0, stream>>>(hidden, emb0, cw, cb, Wg, Wo, out);
}

// Round 5
// 79.029 us; speedup vs baseline: 1.3120x; 1.1487x over previous
//
#include <hip/hip_runtime.h>
#include <hip/hip_bf16.h>
#include <stdint.h>

#define HSZ 2048
#define PRIME 500009u
#define CHUNK 64   // K-chunk (floats) of hidden staged per iteration
#define NCH 32     // 2048 / 64

typedef __attribute__((ext_vector_type(8))) short short8;
typedef __attribute__((ext_vector_type(4))) float f32x4;
typedef __attribute__((ext_vector_type(4))) unsigned uint4v;
typedef __attribute__((ext_vector_type(2))) unsigned uint2v;

#define MEMFENCE asm volatile("" ::: "memory")
#define BARRIER() do { MEMFENCE; __builtin_amdgcn_s_barrier(); MEMFENCE; } while (0)
#define WAIT_LGKM0 asm volatile("s_waitcnt lgkmcnt(0)" ::: "memory")
#define WAIT_VM(n) asm volatile("s_waitcnt vmcnt(" #n ")" ::: "memory")

// hw bf16 cvt (v_cvt_pk_bf16_f32), RNE
__device__ __forceinline__ unsigned pk2(float x, float y) {
  __hip_bfloat162 h = __float22bfloat162_rn(make_float2(x, y));
  return *reinterpret_cast<unsigned*>(&h);
}
__device__ __forceinline__ short f2bf(float f) {
  __hip_bfloat16 h = __float2bfloat16(f);
  return *reinterpret_cast<short*>(&h);
}
__device__ __forceinline__ short8 pack8(float4 a, float4 b) {
  uint4v u = {pk2(a.x, a.y), pk2(a.z, a.w), pk2(b.x, b.y), pk2(b.z, b.w)};
  return __builtin_bit_cast(short8, u);
}
__device__ __forceinline__ short8 load8_bf(const float* __restrict__ p) {
  float4 a = *reinterpret_cast<const float4*>(p);
  float4 b = *reinterpret_cast<const float4*>(p + 4);
  return pack8(a, b);
}
// async global->LDS, 16B/lane, LDS dest = wave-uniform base + lane*16 (linear)
__device__ __forceinline__ void gload_lds16(const float* g, void* l) {
  __builtin_amdgcn_global_load_lds(
      (const __attribute__((address_space(1))) void*)g,
      (__attribute__((address_space(3))) void*)l, 16, 0, 0);
}

// ================= fully-fused kernel: 512 blocks x 256 threads, 32 tokens/block ==========
// phases: hash(48 slots) -> gather -> emb0 MFMA -> conv (block-local via 16-token lookback)
//         -> gate MLP (pipelined hidden staging, counted vmcnt) -> sigmoid*emb -> @Wo.T
__global__ __launch_bounds__(256, 2) void engram_fused(
    const int* __restrict__ ids, const int* __restrict__ mapping,
    const unsigned* __restrict__ mult, const float* __restrict__ table,
    const float* __restrict__ Wh, const float* __restrict__ hidden,
    const float* __restrict__ cw, const float* __restrict__ cb,
    const float* __restrict__ Wg, const float* __restrict__ Wo,
    float* __restrict__ out) {
  __shared__ __align__(16) float hbuf[2][32][CHUNK];  // 16 KB hidden double buffer
  __shared__ __align__(16) short A_lds[48][264];      // gathered table rows, bf16
  __shared__ __align__(16) float emb48[48][36];       // emb0 for 48 slots (16-pad row)
  __shared__ float emb_c[32][33];                     // conv output
  __shared__ __align__(16) short ge_lds[32][40];      // gate*emb bf16
  __shared__ int idx_lds[384];                        // 48 slots x 8 heads

  const int tid = threadIdx.x;
  const int wid = tid >> 6, lane = tid & 63;
  const int l16 = lane & 15, q = lane >> 4;
  const int t0 = blockIdx.x * 32;

  // stage one 32 x CHUNK f32 chunk of hidden; wave w covers rows w*8..w*8+7 in 2 instrs.
  // LDS dest linear; global src byte-XOR-swizzled by ((row&7)<<4) (read side matches).
  auto STAGE = [&](int buf, int kc) {
#pragma unroll
    for (int j = 0; j < 2; ++j) {
      int r = wid * 8 + j * 4 + (lane >> 4);
      unsigned c4 = (((unsigned)l16 * 16u) ^ (((unsigned)r & 7u) << 4)) >> 2;  // float idx
      const float* src = hidden + (size_t)(t0 + r) * HSZ + kc * CHUNK + c4;
      gload_lds16(src, &hbuf[buf][wid * 8 + j * 4][0]);
    }
  };

  STAGE(0, 0);
  STAGE(1, 1);  // chunks 0,1 fly under the whole emb0 front-end

  // ---- 1) hash: 48 slots x 8 heads; slot i = token t0-16+i (clamped; masked later) ----
#pragma unroll
  for (int p = 0; p < 2; ++p) {
    int hh = p * 256 + tid;
    if (hh < 384) {
      int slot = hh >> 3, head = hh & 7;
      int tg = t0 - 16 + slot;
      if (tg < 0) tg = 0;
      int b = tg >> 12, s = tg & 4095;
      const int* idb = ids + (b << 12);
      int s1 = s + 1 > 4095 ? 4095 : s + 1;
      int s2 = s + 2 > 4095 ? 4095 : s + 2;
      uint64_t c0 = (unsigned)mapping[idb[s]];
      uint64_t c1 = (unsigned)mapping[idb[s1]];
      uint64_t c2 = (unsigned)mapping[idb[s2]];
      int mb = head * 3;  // multipliers row-major [2][4][3]
      uint64_t h = (c0 * (uint64_t)mult[mb]) ^ (c1 * (uint64_t)mult[mb + 1]);
      if (head >= 4) h ^= c2 * (uint64_t)mult[mb + 2];
      idx_lds[hh] = (int)((unsigned)(h % PRIME) + (unsigned)head * PRIME);
    }
  }
  WAIT_LGKM0; BARRIER();

  // ---- 2) gather 384 table rows (128 B each, 8 lanes/row) -> A_lds bf16 ----
#pragma unroll
  for (int p = 0; p < 12; ++p) {
    int r = p * 32 + (tid >> 3);
    int c4 = (tid & 7) * 4;
    int row = idx_lds[r];
    float4 v = *reinterpret_cast<const float4*>(table + (size_t)row * 32 + c4);
    uint2v pk = {pk2(v.x, v.y), pk2(v.z, v.w)};
    *reinterpret_cast<uint2v*>(&A_lds[r >> 3][(r & 7) * 32 + c4]) = pk;
  }
  WAIT_LGKM0; BARRIER();

  // ---- 3) emb0 MFMA: 6 jobs (3 token-tiles x 2 e-tiles), swapped operands ----
  for (int job = wid; job < 6; job += 4) {
    int jt = job >> 1, e0 = (job & 1) * 16;
    f32x4 acc = {0.f, 0.f, 0.f, 0.f};
#pragma unroll
    for (int ks = 0; ks < 8; ++ks) {
      short8 wf = load8_bf(Wh + (size_t)(e0 + l16) * 256 + ks * 32 + q * 8);
      short8 a = *reinterpret_cast<const short8*>(&A_lds[jt * 16 + l16][ks * 32 + q * 8]);
      acc = __builtin_amdgcn_mfma_f32_16x16x32_bf16(wf, a, acc, 0, 0, 0);
    }
    // D: col=token(l16), row=e(q*4+j) -> 16B store
    *reinterpret_cast<f32x4*>(&emb48[jt * 16 + l16][e0 + q * 4]) = acc;
  }
  WAIT_LGKM0; BARRIER();

  // ---- 4) conv: emb_c[tl][e] = cb + sum_j cw[e,j]*emb48[13+tl+j][e] (batch zero-pad) ----
#pragma unroll
  for (int it = 0; it < 4; ++it) {
    int ii = it * 256 + tid;
    int tl = ii >> 5, e = ii & 31;
    int s = (t0 & 4095) + tl;
    float a = cb[e];
#pragma unroll
    for (int j = 0; j < 4; ++j)
      if (s - 3 + j >= 0) a += cw[e * 4 + j] * emb48[13 + tl + j][e];
    emb_c[tl][e] = a;
  }
  WAIT_LGKM0; BARRIER();

  // ---- 5) gate MLP: wave (tt,ee) owns 16x16 tile, full K; counted-vmcnt pipeline ----
  const int tt = wid >> 1, ee = wid & 1;
  const int R = tt * 16 + l16;
  const unsigned sw = ((unsigned)R & 7u) << 4;
  const char* hb0 = (const char*)&hbuf[0][R][0];
  const char* hb1 = (const char*)&hbuf[1][R][0];
  const float* wgp = Wg + (size_t)(ee * 16 + l16) * HSZ + q * 8;
  f32x4 acc = {0.f, 0.f, 0.f, 0.f};

  for (int kc = 0; kc < NCH - 1; ++kc) {
    WAIT_VM(8);   // chunk kc landed; chunk kc+1 may still fly
    BARRIER();
    const char* hb = (kc & 1) ? hb1 : hb0;
    unsigned x0 = q * 32u;
    float4 a0 = *reinterpret_cast<const float4*>(hb + (x0 ^ sw));
    float4 a1 = *reinterpret_cast<const float4*>(hb + ((x0 + 16) ^ sw));
    float4 a2 = *reinterpret_cast<const float4*>(hb + ((x0 + 128) ^ sw));
    float4 a3 = *reinterpret_cast<const float4*>(hb + ((x0 + 144) ^ sw));
    short8 A0 = pack8(a0, a1);
    short8 A1 = pack8(a2, a3);
    short8 B0 = load8_bf(wgp + kc * CHUNK);
    short8 B1 = load8_bf(wgp + kc * CHUNK + 32);
    WAIT_LGKM0;   // all our ds_reads of chunk kc are in regs
    BARRIER();    // => every wave done reading buf[kc&1]; safe to overwrite
    if (kc < NCH - 2) STAGE(kc & 1, kc + 2);  // prefetch flies across barriers
    acc = __builtin_amdgcn_mfma_f32_16x16x32_bf16(A0, B0, acc, 0, 0, 0);
    acc = __builtin_amdgcn_mfma_f32_16x16x32_bf16(A1, B1, acc, 0, 0, 0);
  }
  {  // final chunk (NCH-1, odd -> hb1), drain fully
    WAIT_VM(0);
    BARRIER();
    unsigned x0 = q * 32u;
    float4 a0 = *reinterpret_cast<const float4*>(hb1 + (x0 ^ sw));
    float4 a1 = *reinterpret_cast<const float4*>(hb1 + ((x0 + 16) ^ sw));
    float4 a2 = *reinterpret_cast<const float4*>(hb1 + ((x0 + 128) ^ sw));
    float4 a3 = *reinterpret_cast<const float4*>(hb1 + ((x0 + 144) ^ sw));
    short8 B0 = load8_bf(wgp + (NCH - 1) * CHUNK);
    short8 B1 = load8_bf(wgp + (NCH - 1) * CHUNK + 32);
    acc = __builtin_amdgcn_mfma_f32_16x16x32_bf16(pack8(a0, a1), B0, acc, 0, 0, 0);
    acc = __builtin_amdgcn_mfma_f32_16x16x32_bf16(pack8(a2, a3), B1, acc, 0, 0, 0);
  }

  // ---- 6) sigmoid * conv-emb -> ge_lds (each wave writes its own 16x16 quadrant) ----
#pragma unroll
  for (int j = 0; j < 4; ++j) {
    int r = tt * 16 + q * 4 + j, c = ee * 16 + l16;
    float g = 1.f / (1.f + __expf(-acc[j]));
    ge_lds[r][c] = f2bf(g * emb_c[r][c]);
  }
  WAIT_LGKM0; BARRIER();

  // ---- 7) out[t,h] = ge @ Wo.T (swapped operands -> float4 stores); 512 h-cols/wave ----
  short8 Af0 = *reinterpret_cast<const short8*>(&ge_lds[l16][q * 8]);
  short8 Af1 = *reinterpret_cast<const short8*>(&ge_lds[16 + l16][q * 8]);
  float* orow0 = out + (size_t)(t0 + l16) * HSZ;
  float* orow1 = out + (size_t)(t0 + 16 + l16) * HSZ;
  int hbase = wid * 512;
  for (int ht = 0; ht < 32; ++ht) {
    int h0 = hbase + ht * 16;
    short8 aw = load8_bf(Wo + (size_t)(h0 + l16) * 32 + q * 8);
    f32x4 z = {0.f, 0.f, 0.f, 0.f};
    f32x4 o0 = __builtin_amdgcn_mfma_f32_16x16x32_bf16(aw, Af0, z, 0, 0, 0);
    f32x4 o1 = __builtin_amdgcn_mfma_f32_16x16x32_bf16(aw, Af1, z, 0, 0, 0);
    *reinterpret_cast<f32x4*>(orow0 + h0 + q * 4) = o0;
    *reinterpret_cast<f32x4*>(orow1 + h0 + q * 4) = o1;
  }
}

extern "C" void kernel_launch(void* const* d_in, const int* in_sizes, int n_in,
                              void* d_out, int out_size, void* d_ws, size_t ws_size,
                              hipStream_t stream) {
  const int* ids = (const int*)d_in[0];
  const float* hidden = (const float*)d_in[1];
  const int* mapping = (const int*)d_in[2];
  const unsigned* mult = (const unsigned*)d_in[3];  // int64 delivered as int32; low bits exact
  const float* table = (const float*)d_in[4];
  const float* cw = (const float*)d_in[5];
  const float* cb = (const float*)d_in[6];
  const float* Wh = (const float*)d_in[7];
  const float* Wg = (const float*)d_in[8];
  const float* Wo = (const float*)d_in[9];
  float* out = (float*)d_out;

  engram_fused<<<512, 256, 0, stream>>>(ids, mapping, mult, table, Wh, hidden,
                                        cw, cb, Wg, Wo, out);
}